// Round 7
// baseline (183.858 us; speedup 1.0000x reference)
//
#include <hip/hip_runtime.h>
#include <stdint.h>

// Sudoku naked-pair elimination, round 7: 3-kernel stream-separated pipeline.
//   K1: 95.5 MB float read  -> 3 MB bit array (pure read stream)
//   K2: 3 MB bits -> 5.3 MB per-cell fin masks (tiny, L2-resident)
//   K3: 5.3 MB fin masks -> 95.5 MB float write (pure write stream)
// Rationale: every fused variant (R1-R6) pinned at 2.2-2.5 TB/s; the
// harness's own fill runs 6.7 TB/s. One-sided streams per kernel.

#define NFLOAT 23887872   // 32768 * 729
#define NBYTE  2985984    // NFLOAT / 8  (bit array bytes; 11664*256 exactly)
#define NBOX   294912     // 32768 * 9
#define NVEC4  5971968    // NFLOAT / 4

// ---- K1: 8 floats -> 1 byte of bits. Dense bit order: bit i == float i.
__global__ __launch_bounds__(256) void k1_compress(
    const float* __restrict__ in, uint8_t* __restrict__ bits) {
  const int t = blockIdx.x * 256 + threadIdx.x;          // < NBYTE
  const float4* in4 = (const float4*)in;
  float4 a = in4[2 * t];
  float4 b = in4[2 * t + 1];
  uint32_t w = (a.x != 0.0f ? 1u : 0u)
             | (a.y != 0.0f ? 2u : 0u)
             | (a.z != 0.0f ? 4u : 0u)
             | (a.w != 0.0f ? 8u : 0u)
             | (b.x != 0.0f ? 16u : 0u)
             | (b.y != 0.0f ? 32u : 0u)
             | (b.z != 0.0f ? 64u : 0u)
             | (b.w != 0.0f ? 128u : 0u);
  bits[t] = (uint8_t)w;
}

// ---- K2: thread per 3x3 box. Extract 27 3-bit groups, naked-pair logic,
// write 9 per-cell fin masks (ushort) at fin[board*81 + cell].
__global__ __launch_bounds__(256) void k2_boxlogic(
    const uint32_t* __restrict__ bw, unsigned short* __restrict__ fin) {
  const int t = blockIdx.x * 256 + threadIdx.x;          // < NBOX
  const int board = t / 9;
  const int bi = t - board * 9;
  const int bo = (bi / 3) * 27 + (bi % 3) * 3;           // box offset in board
  const int S = board * 729;                             // board bit base

  // Extract 3 bits per (d, r): cells (r*3 .. r*3+2) of this box, digit d.
  uint32_t cellm[9] = {0, 0, 0, 0, 0, 0, 0, 0, 0};
#pragma unroll
  for (int d = 0; d < 9; ++d)
#pragma unroll
    for (int r = 0; r < 3; ++r) {
      const int f = S + d * 81 + bo + r * 9;             // global bit index
      const int idx = f >> 5, sh = f & 31;
      // safe: max idx+1 == 746495 < 746496 total dwords
      const uint64_t v = (uint64_t)bw[idx] | ((uint64_t)bw[idx + 1] << 32);
      const uint32_t b3 = (uint32_t)(v >> sh) & 7u;
      cellm[r * 3 + 0] |= (b3 & 1u) << d;
      cellm[r * 3 + 1] |= ((b3 >> 1) & 1u) << d;
      cellm[r * 3 + 2] |= ((b3 >> 2) & 1u) << d;
    }

  uint32_t pairm[9];
#pragma unroll
  for (int j = 0; j < 9; ++j)
    pairm[j] = (__popc(cellm[j]) == 2) ? cellm[j] : 0u;

  bool naked[9];
#pragma unroll
  for (int j = 0; j < 9; ++j) {
    int cnt = 0;
#pragma unroll
    for (int k = 0; k < 9; ++k) cnt += (pairm[k] == pairm[j]);
    naked[j] = (pairm[j] != 0u) && (cnt == 2);
  }

  // Erase by pair VALUE (R5's bitwise shortcut was wrong; this is R6-verified)
  unsigned short* fb = fin + board * 81;
#pragma unroll
  for (int j = 0; j < 9; ++j) {
    uint32_t er = 0;
#pragma unroll
    for (int k = 0; k < 9; ++k)
      if (naked[k] && pairm[k] != pairm[j]) er |= pairm[k];
    const int cell = bo + (j / 3) * 9 + (j % 3);
    fb[cell] = (unsigned short)(cellm[j] & ~er);
  }
}

// ---- K3: thread per output float4. 4 fin-mask lookups + bit test + dwordx4.
__global__ __launch_bounds__(256) void k3_expand(
    const unsigned short* __restrict__ fin, float* __restrict__ out) {
  const int t = blockIdx.x * 256 + threadIdx.x;          // < NVEC4
  const int e0 = t * 4;
  float4 v;
  float* vp = &v.x;
#pragma unroll
  for (int q = 0; q < 4; ++q) {
    const int e = e0 + q;                                // flat float index
    const int b = e / 729;
    const int rem = e - b * 729;
    const int d = rem / 81;
    const int cell = rem - d * 81;
    vp[q] = (float)((fin[b * 81 + cell] >> d) & 1u);
  }
  ((float4*)out)[t] = v;
}

extern "C" void kernel_launch(void* const* d_in, const int* in_sizes, int n_in,
                              void* d_out, int out_size, void* d_ws, size_t ws_size,
                              hipStream_t stream) {
  const float* mask = (const float*)d_in[0];
  float* out = (float*)d_out;
  uint8_t* bits = (uint8_t*)d_ws;                        // NBYTE bytes
  unsigned short* fin = (unsigned short*)((uint8_t*)d_ws + NBYTE);  // 81*32768 ushorts

  k1_compress<<<NBYTE / 256, 256, 0, stream>>>(mask, bits);
  k2_boxlogic<<<NBOX / 256, 256, 0, stream>>>((const uint32_t*)bits, fin);
  k3_expand<<<NVEC4 / 256, 256, 0, stream>>>(fin, out);
}